// Round 2
// baseline (816.136 us; speedup 1.0000x reference)
//
#include <hip/hip_runtime.h>
#include <math.h>

#define N_ATOM 2048
#define NTOK   512
#define CC     128
#define CZDIM  16
#define HH     4
#define CHD    32
#define NHID   256
#define NQB    64     // 2048 / 32 query blocks
#define R1     4      // rows per workgroup in K1/K3 (grid 512 -> 2 blocks/CU)

__device__ __forceinline__ float sigm(float x) { return 1.0f / (1.0f + __expf(-x)); }

// ---------------------------------------------------------------------------
// amask_bias[l] = (sum_i a2t[l,i]*tm[i] - 1) * 1e9     (additive key mask)
__global__ __launch_bounds__(256) void k_amask(const float* __restrict__ a2t,
                                               const float* __restrict__ tm,
                                               float* __restrict__ amask) {
    int wave = threadIdx.x >> 6, lane = threadIdx.x & 63;
    int l = blockIdx.x * 4 + wave;
    float s = 0.0f;
    for (int i = lane; i < NTOK; i += 64) s += a2t[(size_t)l * NTOK + i] * tm[i];
    for (int m = 1; m < 64; m <<= 1) s += __shfl_xor(s, m);
    if (lane == 0) amask[l] = (s - 1.0f) * 1e9f;
}

// ---------------------------------------------------------------------------
// K1: per-row AdaLN (both) + all row matvecs. grid 512 (4 rows each), block 256.
// Thread layout: wave r owns row r (64 lanes); lane l owns output cols {2l,2l+1}
// (or {4l..4l+3} for the 256-wide transition hidden).
__global__ __launch_bounds__(256) void k_adaln_proj(
    const float* __restrict__ a, const float* __restrict__ cl,
    const float* __restrict__ gs1, const float* __restrict__ ws1,
    const float* __restrict__ bs1, const float* __restrict__ wsb1,
    const float* __restrict__ wq, const float* __restrict__ bq,
    const float* __restrict__ wk, const float* __restrict__ wv,
    const float* __restrict__ wg,
    const float* __restrict__ wog1, const float* __restrict__ bog1,
    const float* __restrict__ gs2, const float* __restrict__ ws2,
    const float* __restrict__ bs2, const float* __restrict__ wsb2,
    const float* __restrict__ wt1, const float* __restrict__ wt2,
    const float* __restrict__ wt3,
    const float* __restrict__ wog2, const float* __restrict__ bog2,
    float* __restrict__ q_o, float* __restrict__ k_o, float* __restrict__ v_o,
    float* __restrict__ g_o, float* __restrict__ og1_o, float* __restrict__ trans_o) {
    __shared__ float lna[R1][CC];   // LN(a)
    __shared__ float sn1[R1][CC];   // LN(cl)*gs1
    __shared__ float sn2[R1][CC];   // LN(cl)*gs2
    __shared__ float cls[R1][CC];   // raw cl
    __shared__ float aln1[R1][CC];  // AdaLN1 output
    __shared__ float a2s[R1][CC];   // AdaLN2 output
    __shared__ float hid[R1][NHID]; // SwiGLU hidden

    const int t = threadIdx.x;
    const int r = t >> 6, l = t & 63;
    const int n = blockIdx.x * R1 + r;

    // ---- load row + both LayerNorms (one wave per row, in registers) ----
    const float* arow = a + (size_t)n * CC;
    const float* crow = cl + (size_t)n * CC;
    float a0 = arow[l], a1 = arow[l + 64];
    float c0 = crow[l], c1 = crow[l + 64];
    float s = a0 + a1, s2 = a0 * a0 + a1 * a1;
    float cs = c0 + c1, cs2 = c0 * c0 + c1 * c1;
#pragma unroll
    for (int m = 1; m < 64; m <<= 1) {
        s += __shfl_xor(s, m); s2 += __shfl_xor(s2, m);
        cs += __shfl_xor(cs, m); cs2 += __shfl_xor(cs2, m);
    }
    float mean = s * (1.0f / 128.0f);
    float rs = rsqrtf(s2 * (1.0f / 128.0f) - mean * mean + 1e-5f);
    float cmean = cs * (1.0f / 128.0f);
    float crs = rsqrtf(cs2 * (1.0f / 128.0f) - cmean * cmean + 1e-5f);
    float cn0 = (c0 - cmean) * crs, cn1 = (c1 - cmean) * crs;
    lna[r][l] = (a0 - mean) * rs; lna[r][l + 64] = (a1 - mean) * rs;
    sn1[r][l] = cn0 * gs1[l];      sn1[r][l + 64] = cn1 * gs1[l + 64];
    sn2[r][l] = cn0 * gs2[l];      sn2[r][l + 64] = cn1 * gs2[l + 64];
    cls[r][l] = c0;                cls[r][l + 64] = c1;
    __syncthreads();

    const int o2 = 2 * l;

    // ---- Stage A: both AdaLN matmuls fused (4 weight streams) ----
    {
        float A1x = 0, A1y = 0, B1x = 0, B1y = 0;
        float A2x = 0, A2y = 0, B2x = 0, B2y = 0;
#pragma unroll 4
        for (int c = 0; c < CC; c++) {
            float x1 = sn1[r][c], x2 = sn2[r][c];
            float2 w1  = *(const float2*)(ws1  + c * CC + o2);
            float2 wb1 = *(const float2*)(wsb1 + c * CC + o2);
            float2 w2  = *(const float2*)(ws2  + c * CC + o2);
            float2 wb2 = *(const float2*)(wsb2 + c * CC + o2);
            A1x += x1 * w1.x;  A1y += x1 * w1.y;
            B1x += x1 * wb1.x; B1y += x1 * wb1.y;
            A2x += x2 * w2.x;  A2y += x2 * w2.y;
            B2x += x2 * wb2.x; B2y += x2 * wb2.y;
        }
        float lx = lna[r][o2], ly = lna[r][o2 + 1];
        aln1[r][o2]     = sigm(A1x + bs1[o2])     * lx + B1x;
        aln1[r][o2 + 1] = sigm(A1y + bs1[o2 + 1]) * ly + B1y;
        a2s[r][o2]      = sigm(A2x + bs2[o2])     * lx + B2x;
        a2s[r][o2 + 1]  = sigm(A2y + bs2[o2 + 1]) * ly + B2y;
    }
    __syncthreads();

    // ---- Stage B: q,k,v,g from aln1; og1,og2-gate from cl (6 weight streams) ----
    float G2x, G2y;  // og2 pre-activation, kept in registers for stage D
    {
        float Aqx = 0, Aqy = 0, Akx = 0, Aky = 0, Avx = 0, Avy = 0, Agx = 0, Agy = 0;
        float Ao1x = 0, Ao1y = 0, Ao2x = 0, Ao2y = 0;
#pragma unroll 4
        for (int c = 0; c < CC; c++) {
            float x  = aln1[r][c];
            float xc = cls[r][c];
            float2 wqv = *(const float2*)(wq   + c * CC + o2);
            float2 wkv = *(const float2*)(wk   + c * CC + o2);
            float2 wvv = *(const float2*)(wv   + c * CC + o2);
            float2 wgv = *(const float2*)(wg   + c * CC + o2);
            float2 w1v = *(const float2*)(wog1 + c * CC + o2);
            float2 w2v = *(const float2*)(wog2 + c * CC + o2);
            Aqx += x * wqv.x;   Aqy += x * wqv.y;
            Akx += x * wkv.x;   Aky += x * wkv.y;
            Avx += x * wvv.x;   Avy += x * wvv.y;
            Agx += x * wgv.x;   Agy += x * wgv.y;
            Ao1x += xc * w1v.x; Ao1y += xc * w1v.y;
            Ao2x += xc * w2v.x; Ao2y += xc * w2v.y;
        }
        size_t base = (size_t)n * CC + o2;
        *(float2*)(q_o + base)   = make_float2(Aqx + bq[o2], Aqy + bq[o2 + 1]);
        *(float2*)(k_o + base)   = make_float2(Akx, Aky);
        *(float2*)(v_o + base)   = make_float2(Avx, Avy);
        *(float2*)(g_o + base)   = make_float2(sigm(Agx), sigm(Agy));
        *(float2*)(og1_o + base) = make_float2(sigm(Ao1x + bog1[o2]), sigm(Ao1y + bog1[o2 + 1]));
        G2x = Ao2x; G2y = Ao2y;
    }

    // ---- Stage C: SwiGLU hidden (256-wide, 4 cols/lane, float4 weights) ----
    {
        const int o4 = 4 * l;
        float T1[4] = {0, 0, 0, 0}, T2[4] = {0, 0, 0, 0};
#pragma unroll 4
        for (int c = 0; c < CC; c++) {
            float x = a2s[r][c];
            float4 w1v = *(const float4*)(wt1 + c * NHID + o4);
            float4 w2v = *(const float4*)(wt2 + c * NHID + o4);
            T1[0] += x * w1v.x; T1[1] += x * w1v.y; T1[2] += x * w1v.z; T1[3] += x * w1v.w;
            T2[0] += x * w2v.x; T2[1] += x * w2v.y; T2[2] += x * w2v.z; T2[3] += x * w2v.w;
        }
        float4 hv;
        hv.x = T1[0] * sigm(T1[0]) * T2[0];
        hv.y = T1[1] * sigm(T1[1]) * T2[1];
        hv.z = T1[2] * sigm(T1[2]) * T2[2];
        hv.w = T1[3] * sigm(T1[3]) * T2[3];
        *(float4*)&hid[r][o4] = hv;
    }
    __syncthreads();

    // ---- Stage D: trans = sigmoid(og2) * (hid @ wt3) ----
    {
        float Ax = 0, Ay = 0;
#pragma unroll 8
        for (int c = 0; c < NHID; c++) {
            float x = hid[r][c];
            float2 w = *(const float2*)(wt3 + c * CC + o2);
            Ax += x * w.x; Ay += x * w.y;
        }
        *(float2*)(trans_o + (size_t)n * CC + o2) =
            make_float2(sigm(G2x + bog2[o2]) * Ax, sigm(G2y + bog2[o2 + 1]) * Ay);
    }
}

// ---------------------------------------------------------------------------
// K_pb: sparse pair bias for ALL 3 transformer blocks in one launch.
// One thread per (b,qb,qi,kj): LN over 16 channels + 4 dots. grid 3072, block 256.
__global__ __launch_bounds__(256) void k_pb(const float* __restrict__ plm,
                                            const float* __restrict__ gz,
                                            const float* __restrict__ bz,
                                            const float* __restrict__ wz,
                                            float* __restrict__ pb) {
    int pid = blockIdx.x * 256 + threadIdx.x;  // 3 * 64*32*128
    int b = pid >> 18;
    int rem = pid & 262143;
    int qb = rem >> 12;
    int qi = (rem >> 7) & 31;
    int kj = rem & 127;
    int n = qb * 32 + qi;
    int kstart = max(0, qb * 32 - 48);
    int m = kstart + kj;
    const float* gzb = gz + b * CZDIM;
    const float* bzb = bz + b * CZDIM;
    const float* wzb = wz + b * CZDIM * HH;
    float out[HH] = {0, 0, 0, 0};
    if (m < N_ATOM) {
        const float* p = plm + ((size_t)n * N_ATOM + m) * CZDIM;
        float x[CZDIM];
        const float4* p4 = (const float4*)p;
#pragma unroll
        for (int i = 0; i < 4; i++) {
            float4 v = p4[i];
            x[4 * i] = v.x; x[4 * i + 1] = v.y; x[4 * i + 2] = v.z; x[4 * i + 3] = v.w;
        }
        float s = 0, s2 = 0;
#pragma unroll
        for (int c = 0; c < CZDIM; c++) { s += x[c]; s2 += x[c] * x[c]; }
        float mean = s * (1.0f / 16.0f);
        float rs = rsqrtf(s2 * (1.0f / 16.0f) - mean * mean + 1e-5f);
#pragma unroll
        for (int c = 0; c < CZDIM; c++) {
            float z = (x[c] - mean) * rs * gzb[c] + bzb[c];
#pragma unroll
            for (int h = 0; h < HH; h++) out[h] += z * wzb[c * HH + h];
        }
    }
#pragma unroll
    for (int h = 0; h < HH; h++)
        pb[(size_t)b * 1048576 + (((qb * HH + h) * 32 + qi) << 7) + kj] = out[h];
}

// ---------------------------------------------------------------------------
// K_attn: one workgroup per (query block, head). 32 queries x <=128 keys.
// Q fragment in registers (qi fixed per thread); float4 LDS reads.
__global__ __launch_bounds__(256) void k_attn(const float* __restrict__ q,
                                              const float* __restrict__ k,
                                              const float* __restrict__ v,
                                              const float* __restrict__ pb,
                                              const float* __restrict__ amask,
                                              float* __restrict__ o_out) {
    __shared__ __align__(16) float qs[32][36];
    __shared__ __align__(16) float ks[128][36];
    __shared__ __align__(16) float vs[128][36];
    __shared__ float ps[32][132];
    const int t = threadIdx.x;
    const int qb = blockIdx.x >> 2, h = blockIdx.x & 3;
    const int n0 = qb * 32;
    const int kstart = max(0, qb * 32 - 48);
    const int nk = min(N_ATOM, qb * 32 + 80) - kstart;

    for (int idx = t; idx < 32 * 32; idx += 256) {
        int qi = idx >> 5, d = idx & 31;
        qs[qi][d] = q[(n0 + qi) * CC + h * CHD + d];
    }
    for (int idx = t; idx < 128 * 32; idx += 256) {
        int kj = idx >> 5, d = idx & 31;
        int m = kstart + kj;
        float kv = 0.0f, vv = 0.0f;
        if (m < N_ATOM) { kv = k[m * CC + h * CHD + d]; vv = v[m * CC + h * CHD + d]; }
        ks[kj][d] = kv; vs[kj][d] = vv;
    }
    __syncthreads();

    const int qi = t >> 3, j8 = t & 7;  // 8 threads per query row (same wave)
    float qreg[32];
#pragma unroll
    for (int i = 0; i < 8; i++) {
        float4 v4 = *(const float4*)&qs[qi][4 * i];
        qreg[4 * i] = v4.x; qreg[4 * i + 1] = v4.y; qreg[4 * i + 2] = v4.z; qreg[4 * i + 3] = v4.w;
    }
    const float isc = 0.17677669529663687f;  // 1/sqrt(32)
    const float* pbrow = pb + ((qb * HH + h) * 32 + qi) * 128;
    float lr[16];
    float mx = -1e30f;
#pragma unroll
    for (int jj = 0; jj < 16; jj++) {
        int kj = j8 + 8 * jj;
        float acc = 0;
#pragma unroll
        for (int i = 0; i < 8; i++) {
            float4 kv = *(const float4*)&ks[kj][4 * i];
            acc += qreg[4 * i] * kv.x + qreg[4 * i + 1] * kv.y
                 + qreg[4 * i + 2] * kv.z + qreg[4 * i + 3] * kv.w;
        }
        float lg = (kj < nk) ? (acc * isc + pbrow[kj] + amask[kstart + kj]) : -1e9f;
        lr[jj] = lg;
        mx = fmaxf(mx, lg);
    }
    for (int m = 1; m < 8; m <<= 1) mx = fmaxf(mx, __shfl_xor(mx, m));
    float sum = 0;
#pragma unroll
    for (int jj = 0; jj < 16; jj++) { lr[jj] = __expf(lr[jj] - mx); sum += lr[jj]; }
    for (int m = 1; m < 8; m <<= 1) sum += __shfl_xor(sum, m);
    float rd = 1.0f / sum;
#pragma unroll
    for (int jj = 0; jj < 16; jj++) ps[qi][j8 + 8 * jj] = lr[jj] * rd;
    __syncthreads();

    const int d0 = (t & 7) * 4;
    float4 acc = {0, 0, 0, 0};
    for (int kj = 0; kj < 128; kj++) {
        float p = ps[qi][kj];
        float4 vv = *(const float4*)&vs[kj][d0];
        acc.x += p * vv.x; acc.y += p * vv.y; acc.z += p * vv.z; acc.w += p * vv.w;
    }
    *(float4*)&o_out[(n0 + qi) * CC + h * CHD + d0] = acc;
}

// ---------------------------------------------------------------------------
// K3: a_new = og1 * ((g*o) @ wo) + trans.  grid 512, 4 rows/block.
__global__ __launch_bounds__(256) void k_combine(const float* __restrict__ g,
                                                 const float* __restrict__ o_in,
                                                 const float* __restrict__ og1,
                                                 const float* __restrict__ trans,
                                                 const float* __restrict__ wo,
                                                 float* __restrict__ a_out) {
    __shared__ float gos[R1][CC];
    const int t = threadIdx.x;
    const int r = t >> 6, l = t & 63;
    const int n = blockIdx.x * R1 + r;
    size_t rbase = (size_t)n * CC;
    gos[r][l]      = g[rbase + l] * o_in[rbase + l];
    gos[r][l + 64] = g[rbase + l + 64] * o_in[rbase + l + 64];
    __syncthreads();
    const int o2 = 2 * l;
    float Ax = 0, Ay = 0;
#pragma unroll 4
    for (int c = 0; c < CC; c++) {
        float x = gos[r][c];
        float2 w = *(const float2*)(wo + c * CC + o2);
        Ax += x * w.x; Ay += x * w.y;
    }
    float2 og = *(const float2*)(og1 + rbase + o2);
    float2 tr = *(const float2*)(trans + rbase + o2);
    *(float2*)(a_out + rbase + o2) = make_float2(og.x * Ax + tr.x, og.y * Ay + tr.y);
}

// ---------------------------------------------------------------------------
extern "C" void kernel_launch(void* const* d_in, const int* in_sizes, int n_in,
                              void* d_out, int out_size, void* d_ws, size_t ws_size,
                              hipStream_t stream) {
    const float* ql   = (const float*)d_in[0];
    const float* cl   = (const float*)d_in[1];
    const float* plm  = (const float*)d_in[2];
    const float* a2t  = (const float*)d_in[3];
    const float* tm   = (const float*)d_in[4];
    const float* ada1_gs  = (const float*)d_in[5];
    const float* ada1_ws  = (const float*)d_in[6];
    const float* ada1_bs  = (const float*)d_in[7];
    const float* ada1_wsb = (const float*)d_in[8];
    const float* wq  = (const float*)d_in[9];
    const float* bq  = (const float*)d_in[10];
    const float* wk  = (const float*)d_in[11];
    const float* wv  = (const float*)d_in[12];
    const float* gz  = (const float*)d_in[13];
    const float* bz  = (const float*)d_in[14];
    const float* wz  = (const float*)d_in[15];
    const float* wg  = (const float*)d_in[16];
    const float* wo  = (const float*)d_in[17];
    const float* wog1 = (const float*)d_in[18];
    const float* bog1 = (const float*)d_in[19];
    const float* ada2_gs  = (const float*)d_in[20];
    const float* ada2_ws  = (const float*)d_in[21];
    const float* ada2_bs  = (const float*)d_in[22];
    const float* ada2_wsb = (const float*)d_in[23];
    const float* wt1 = (const float*)d_in[24];
    const float* wt2 = (const float*)d_in[25];
    const float* wt3 = (const float*)d_in[26];
    const float* wog2 = (const float*)d_in[27];
    const float* bog2 = (const float*)d_in[28];

    const size_t NC = (size_t)N_ATOM * CC;  // 262144
    float* ws = (float*)d_ws;
    float* a_cur  = ws;
    float* qb_    = ws + 1 * NC;
    float* kb_    = ws + 2 * NC;
    float* vb_    = ws + 3 * NC;
    float* gb_    = ws + 4 * NC;
    float* og1b_  = ws + 5 * NC;
    float* transb = ws + 6 * NC;
    float* ob_    = ws + 7 * NC;
    float* pbb_   = ws + 8 * NC;                 // 3 * 1048576 floats
    float* amaskb = ws + 8 * NC + 3 * 1048576;   // 2048 floats

    k_amask<<<N_ATOM / 4, 256, 0, stream>>>(a2t, tm, amaskb);
    k_pb<<<3 * 1024, 256, 0, stream>>>(plm, gz, bz, wz, pbb_);

    for (int b = 0; b < 3; b++) {
        k_adaln_proj<<<N_ATOM / R1, 256, 0, stream>>>(
            (b == 0) ? ql : a_cur, cl,
            ada1_gs + b * CC, ada1_ws + b * CC * CC, ada1_bs + b * CC, ada1_wsb + b * CC * CC,
            wq + b * CC * CC, bq + b * CC, wk + b * CC * CC, wv + b * CC * CC, wg + b * CC * CC,
            wog1 + b * CC * CC, bog1 + b * CC,
            ada2_gs + b * CC, ada2_ws + b * CC * CC, ada2_bs + b * CC, ada2_wsb + b * CC * CC,
            wt1 + b * CC * NHID, wt2 + b * CC * NHID, wt3 + b * NHID * CC,
            wog2 + b * CC * CC, bog2 + b * CC,
            qb_, kb_, vb_, gb_, og1b_, transb);
        k_attn<<<NQB * HH, 256, 0, stream>>>(qb_, kb_, vb_, pbb_ + (size_t)b * 1048576,
                                             amaskb, ob_);
        k_combine<<<N_ATOM / R1, 256, 0, stream>>>(gb_, ob_, og1b_, transb,
                                                   wo + b * CC * CC,
                                                   (b == 2) ? (float*)d_out : a_cur);
    }
}